// Round 1
// baseline (186.566 us; speedup 1.0000x reference)
//
#include <hip/hip_runtime.h>
#include <cstdint>
#include <cstddef>

typedef short bf16x8 __attribute__((ext_vector_type(8)));
typedef float f32x4 __attribute__((ext_vector_type(4)));

__device__ __forceinline__ unsigned short f2bf(float f) {
    union { float f; uint32_t u; } v; v.f = f;
    uint32_t r = v.u + 0x7FFFu + ((v.u >> 16) & 1u);   // round-to-nearest-even
    return (unsigned short)(r >> 16);
}

// ---------------- prep kernels ----------------

__global__ void cast_x_kernel(const float* __restrict__ in,
                              unsigned short* __restrict__ out, int n4) {
    int i = blockIdx.x * blockDim.x + threadIdx.x;
    if (i < n4) {
        float4 v = ((const float4*)in)[i];
        ushort4 o;
        o.x = f2bf(v.x); o.y = f2bf(v.y); o.z = f2bf(v.z); o.w = f2bf(v.w);
        ((ushort4*)out)[i] = o;
    }
}

// Bt[n][k] = bf16(B[k][n]).  B is (H x H) row-major (n contiguous).
__global__ void transpose_cast_b(const float* __restrict__ B,
                                 unsigned short* __restrict__ Bt, int H) {
    __shared__ float tile[32][33];
    int bx = blockIdx.x * 32;   // n tile
    int by = blockIdx.y * 32;   // k tile
    int tx = threadIdx.x, ty = threadIdx.y;  // block (32,8)
#pragma unroll
    for (int i = 0; i < 32; i += 8)
        tile[ty + i][tx] = B[(size_t)(by + ty + i) * H + bx + tx];
    __syncthreads();
#pragma unroll
    for (int i = 0; i < 32; i += 8)
        Bt[(size_t)(bx + ty + i) * H + by + tx] = f2bf(tile[tx][ty + i]);
}

// ---------------- GEMM: C = A(bf16, MxK) * Bt(bf16, NxK)^T -> fp32 MxN -------
// m97 structure: 128x128 tile, BK=32, 4 waves, global_load_lds width=16,
// 16x16x32 bf16 MFMA, 4x4 acc tiles per wave.

__global__ __launch_bounds__(256, 2) void gemm_bf16(
    const unsigned short* __restrict__ A,
    const unsigned short* __restrict__ Bt,
    float* __restrict__ C, int M, int N, int K)
{
    __shared__ __attribute__((aligned(16))) unsigned short sA[128 * 32];
    __shared__ __attribute__((aligned(16))) unsigned short sB[128 * 32];

    const int tid  = threadIdx.x;
    const int wave = tid >> 6;
    const int lane = tid & 63;
    const int m0 = blockIdx.y * 128;
    const int n0 = blockIdx.x * 128;

    // staging: lane l of instruction (wave,i) loads row = wave*32+i*16+l/4,
    // cols [(l&3)*8, +8) -> LDS element (wave*2+i)*512 + l*8  (= base + l*16B)
    const int lrow = lane >> 2;
    const int lcol = (lane & 3) * 8;

    // fragment indices
    const int quad = lane >> 4;      // 0..3
    const int l16  = lane & 15;
    const int wm = wave >> 1;        // wave's 64x64 sub-tile
    const int wn = wave & 1;

    f32x4 acc[4][4];
#pragma unroll
    for (int i = 0; i < 4; ++i)
#pragma unroll
        for (int j = 0; j < 4; ++j)
            acc[i][j] = (f32x4){0.f, 0.f, 0.f, 0.f};

    const unsigned short* Ab = A  + (size_t)m0 * K;
    const unsigned short* Bb = Bt + (size_t)n0 * K;

    for (int k0 = 0; k0 < K; k0 += 32) {
#pragma unroll
        for (int i = 0; i < 2; ++i) {
            const unsigned short* ga =
                Ab + (size_t)(wave * 32 + i * 16 + lrow) * K + (k0 + lcol);
            __builtin_amdgcn_global_load_lds(
                (const __attribute__((address_space(1))) void*)ga,
                (__attribute__((address_space(3))) void*)(sA + (wave * 2 + i) * 512),
                16, 0, 0);
            const unsigned short* gb =
                Bb + (size_t)(wave * 32 + i * 16 + lrow) * K + (k0 + lcol);
            __builtin_amdgcn_global_load_lds(
                (const __attribute__((address_space(1))) void*)gb,
                (__attribute__((address_space(3))) void*)(sB + (wave * 2 + i) * 512),
                16, 0, 0);
        }
        __syncthreads();

        bf16x8 af[4], bfr[4];
#pragma unroll
        for (int t = 0; t < 4; ++t) {
            af[t]  = *(const bf16x8*)(sA + (wm * 64 + t * 16 + l16) * 32 + quad * 8);
            bfr[t] = *(const bf16x8*)(sB + (wn * 64 + t * 16 + l16) * 32 + quad * 8);
        }
#pragma unroll
        for (int im = 0; im < 4; ++im)
#pragma unroll
            for (int in = 0; in < 4; ++in)
                acc[im][in] = __builtin_amdgcn_mfma_f32_16x16x32_bf16(
                    af[im], bfr[in], acc[im][in], 0, 0, 0);
        __syncthreads();
    }

    // epilogue: D[row][col], col = l16, row = quad*4 + r within each 16x16 tile
#pragma unroll
    for (int im = 0; im < 4; ++im) {
#pragma unroll
        for (int in = 0; in < 4; ++in) {
            int col = n0 + wn * 64 + in * 16 + l16;
#pragma unroll
            for (int r = 0; r < 4; ++r) {
                int row = m0 + wm * 64 + im * 16 + quad * 4 + r;
                C[(size_t)row * N + col] = acc[im][in][r];
            }
        }
    }
}

// ---------------- scan kernels ----------------
// y[t] = a*y[t-1] + s[t].  |a| <= 0.03125, so a 12-term window reconstructs
// any chunk's carry-in to ~1e-17 -> chunk-parallel scan is exact in fp32.

__global__ void scan_init_kernel(const float* __restrict__ S,
                                 const float* __restrict__ a_diag,
                                 float* __restrict__ yinit,
                                 int H, int chunk, int W) {
    int tid = blockIdx.x * blockDim.x + threadIdx.x;
    int h = tid % H, c = tid / H;
    float a = a_diag[h];
    float y = 0.f;
    if (c > 0) {
        int t0 = c * chunk;
        for (int t = t0 - W; t < t0; ++t)
            y = fmaf(a, y, S[(size_t)t * H + h]);
    }
    yinit[(size_t)c * H + h] = y;
}

__global__ void scan_run_kernel(const float* __restrict__ yinit,
                                const float* __restrict__ a_diag,
                                float* __restrict__ out,
                                int H, int chunk) {
    int tid = blockIdx.x * blockDim.x + threadIdx.x;
    int h = tid % H, c = tid / H;
    float a = a_diag[h];
    float y = yinit[(size_t)c * H + h];
    size_t base = (size_t)c * chunk * H + h;
    for (int t = 0; t < chunk; ++t) {
        float s = out[base + (size_t)t * H];
        y = fmaf(a, y, s);
        out[base + (size_t)t * H] = y;
    }
}

// ---------------- fallback (tiny ws): correct but slow ----------------

__global__ void gemm_fallback(const float* __restrict__ X, const float* __restrict__ B,
                              float* __restrict__ C, int M, int N, int K) {
    __shared__ float sA[16][17];
    __shared__ float sB[16][17];
    int tx = threadIdx.x, ty = threadIdx.y;
    int row = blockIdx.y * 16 + ty, col = blockIdx.x * 16 + tx;
    float acc = 0.f;
    for (int k0 = 0; k0 < K; k0 += 16) {
        sA[ty][tx] = (row < M && k0 + tx < K) ? X[(size_t)row * K + k0 + tx] : 0.f;
        sB[ty][tx] = (k0 + ty < K && col < N) ? B[(size_t)(k0 + ty) * N + col] : 0.f;
        __syncthreads();
#pragma unroll
        for (int kk = 0; kk < 16; ++kk) acc += sA[ty][kk] * sB[kk][tx];
        __syncthreads();
    }
    if (row < M && col < N) C[(size_t)row * N + col] = acc;
}

__global__ void scan_serial(float* __restrict__ out, const float* __restrict__ a_diag,
                            int T, int H) {
    int h = blockIdx.x * blockDim.x + threadIdx.x;
    if (h >= H) return;
    float a = a_diag[h], y = 0.f;
    for (int t = 0; t < T; ++t) {
        y = fmaf(a, y, out[(size_t)t * H + h]);
        out[(size_t)t * H + h] = y;
    }
}

// ---------------- launch ----------------

extern "C" void kernel_launch(void* const* d_in, const int* in_sizes, int n_in,
                              void* d_out, int out_size, void* d_ws, size_t ws_size,
                              hipStream_t stream) {
    const float* x = (const float*)d_in[0];   // (T,H)
    const float* a = (const float*)d_in[1];   // (H,)
    const float* b = (const float*)d_in[2];   // (H,H)
    float* out = (float*)d_out;               // (T,H)

    const int H = in_sizes[1];
    const int T = in_sizes[0] / H;
    const int M = T, N = H, K = H;

    const int CHUNK = 128, W = 12;

    size_t xbf_elems = (size_t)M * K;
    size_t bt_elems  = (size_t)N * K;
    int nchunks = (T % CHUNK == 0) ? T / CHUNK : 0;
    size_t need = xbf_elems * 2 + bt_elems * 2 + (size_t)nchunks * H * 4 + 256;

    bool fast = (ws_size >= need) && (M % 128 == 0) && (N % 128 == 0) &&
                (K % 32 == 0) && (H % 32 == 0) && nchunks > 0 &&
                ((xbf_elems % 4) == 0);

    if (fast) {
        unsigned short* Xbf = (unsigned short*)d_ws;
        unsigned short* Bt  = Xbf + xbf_elems;
        float* yinit = (float*)(Bt + bt_elems);

        int n4 = (int)(xbf_elems / 4);
        cast_x_kernel<<<(n4 + 255) / 256, 256, 0, stream>>>(x, Xbf, n4);

        dim3 tb(32, 8), tg(H / 32, H / 32);
        transpose_cast_b<<<tg, tb, 0, stream>>>(b, Bt, H);

        dim3 gg(N / 128, M / 128);
        gemm_bf16<<<gg, 256, 0, stream>>>(Xbf, Bt, out, M, N, K);

        int nth = nchunks * H;
        scan_init_kernel<<<nth / 256, 256, 0, stream>>>(out, a, yinit, H, CHUNK, W);
        scan_run_kernel<<<nth / 256, 256, 0, stream>>>(yinit, a, out, H, CHUNK);
    } else {
        dim3 tb(16, 16), tg((N + 15) / 16, (M + 15) / 16);
        gemm_fallback<<<tg, tb, 0, stream>>>(x, b, out, M, N, K);
        scan_serial<<<(H + 255) / 256, 256, 0, stream>>>(out, a, T, H);
    }
}

// Round 2
// 158.088 us; speedup vs baseline: 1.1801x; 1.1801x over previous
//
#include <hip/hip_runtime.h>
#include <cstdint>
#include <cstddef>

typedef short bf16x8 __attribute__((ext_vector_type(8)));
typedef float f32x4 __attribute__((ext_vector_type(4)));

__device__ __forceinline__ unsigned short f2bf(float f) {
    union { float f; uint32_t u; } v; v.f = f;
    uint32_t r = v.u + 0x7FFFu + ((v.u >> 16) & 1u);   // round-to-nearest-even
    return (unsigned short)(r >> 16);
}

// ---------------- prep kernels ----------------

__global__ void cast_x_kernel(const float* __restrict__ in,
                              unsigned short* __restrict__ out, int n4) {
    int i = blockIdx.x * blockDim.x + threadIdx.x;
    if (i < n4) {
        float4 v = ((const float4*)in)[i];
        ushort4 o;
        o.x = f2bf(v.x); o.y = f2bf(v.y); o.z = f2bf(v.z); o.w = f2bf(v.w);
        ((ushort4*)out)[i] = o;
    }
}

// Bt[n][k] = bf16(B[k][n]).  B is (H x H) row-major (n contiguous).
__global__ void transpose_cast_b(const float* __restrict__ B,
                                 unsigned short* __restrict__ Bt, int H) {
    __shared__ float tile[32][33];
    int bx = blockIdx.x * 32;   // n tile
    int by = blockIdx.y * 32;   // k tile
    int tx = threadIdx.x, ty = threadIdx.y;  // block (32,8)
#pragma unroll
    for (int i = 0; i < 32; i += 8)
        tile[ty + i][tx] = B[(size_t)(by + ty + i) * H + bx + tx];
    __syncthreads();
#pragma unroll
    for (int i = 0; i < 32; i += 8)
        Bt[(size_t)(bx + ty + i) * H + by + tx] = f2bf(tile[tx][ty + i]);
}

// ---------------- GEMM: C = A(bf16, MxK) * Bt(bf16, NxK)^T -> fp32 MxN -------
// 128x128 tile, BK=64 (half the barriers of BK=32), 4 waves,
// global_load_lds width=16 with XOR-swizzled LDS layout (kills the 8-way
// ds_read_b128 bank conflicts), 16x16x32 bf16 MFMA, 4x4 acc tiles per wave.
//
// LDS layout (per 128x64 tile): 16 blocks of 1KB; block t = rows t*8..t*8+7.
// Element (row R, 8-elem colblk c) lives at byte offset
//   (R>>3)*1024 + (R&7)*128 + ((c ^ (R&7)) * 16)
// Staging lane l of instr (wave,i): t=wave*4+i, row=t*8+(l>>3),
//   global colblk = (l&7) ^ ((l>>3)&7)  -> LDS slot l*16B (HW lane scatter).
// Read quartet = (kk*4+quad) ^ (l16&7): all 8 quartets hit, 2-way only.

__global__ __launch_bounds__(256, 2) void gemm_bf16(
    const unsigned short* __restrict__ A,
    const unsigned short* __restrict__ Bt,
    float* __restrict__ C, int M, int N, int K)
{
    __shared__ __attribute__((aligned(16))) unsigned short sA[128 * 64];
    __shared__ __attribute__((aligned(16))) unsigned short sB[128 * 64];

    const int tid  = threadIdx.x;
    const int wave = tid >> 6;
    const int lane = tid & 63;
    const int m0 = blockIdx.y * 128;
    const int n0 = blockIdx.x * 128;

    // staging indices
    const int srow = lane >> 3;                      // 0..7 within 8-row block
    const int scol = ((lane & 7) ^ srow) * 8;        // swizzled 8-elem colblk

    // fragment indices
    const int quad = lane >> 4;      // 0..3
    const int l16  = lane & 15;
    const int wm = wave >> 1;        // wave's 64x64 sub-tile
    const int wn = wave & 1;

    const int s7 = l16 & 7;
    const int rbaseA = (wm * 8 + (l16 >> 3)) * 1024 + s7 * 128;
    const int rbaseB = (wn * 8 + (l16 >> 3)) * 1024 + s7 * 128;
    const int coff0 = (quad ^ s7) * 16;              // kk=0 colblk offset
    const int coff1 = ((quad + 4) ^ s7) * 16;        // kk=1 colblk offset

    f32x4 acc[4][4];
#pragma unroll
    for (int i = 0; i < 4; ++i)
#pragma unroll
        for (int j = 0; j < 4; ++j)
            acc[i][j] = (f32x4){0.f, 0.f, 0.f, 0.f};

    const unsigned short* Ab = A  + (size_t)m0 * K;
    const unsigned short* Bb = Bt + (size_t)n0 * K;

    for (int k0 = 0; k0 < K; k0 += 64) {
#pragma unroll
        for (int i = 0; i < 4; ++i) {
            const int t = wave * 4 + i;
            const unsigned short* ga =
                Ab + (size_t)(t * 8 + srow) * K + (k0 + scol);
            __builtin_amdgcn_global_load_lds(
                (const __attribute__((address_space(1))) void*)ga,
                (__attribute__((address_space(3))) void*)(sA + t * 512),
                16, 0, 0);
            const unsigned short* gb =
                Bb + (size_t)(t * 8 + srow) * K + (k0 + scol);
            __builtin_amdgcn_global_load_lds(
                (const __attribute__((address_space(1))) void*)gb,
                (__attribute__((address_space(3))) void*)(sB + t * 512),
                16, 0, 0);
        }
        __syncthreads();

        bf16x8 af[2][4], bfr[2][4];
#pragma unroll
        for (int t = 0; t < 4; ++t) {
            const char* pa = (const char*)sA + rbaseA + t * 2048;
            af[0][t]  = *(const bf16x8*)(pa + coff0);
            af[1][t]  = *(const bf16x8*)(pa + coff1);
            const char* pb = (const char*)sB + rbaseB + t * 2048;
            bfr[0][t] = *(const bf16x8*)(pb + coff0);
            bfr[1][t] = *(const bf16x8*)(pb + coff1);
        }
#pragma unroll
        for (int kk = 0; kk < 2; ++kk)
#pragma unroll
            for (int im = 0; im < 4; ++im)
#pragma unroll
                for (int in = 0; in < 4; ++in)
                    acc[im][in] = __builtin_amdgcn_mfma_f32_16x16x32_bf16(
                        af[kk][im], bfr[kk][in], acc[im][in], 0, 0, 0);
        __syncthreads();
    }

    // epilogue: D[row][col], col = l16, row = quad*4 + r within each 16x16 tile
#pragma unroll
    for (int im = 0; im < 4; ++im) {
#pragma unroll
        for (int in = 0; in < 4; ++in) {
            int col = n0 + wn * 64 + in * 16 + l16;
#pragma unroll
            for (int r = 0; r < 4; ++r) {
                int row = m0 + wm * 64 + im * 16 + quad * 4 + r;
                C[(size_t)row * N + col] = acc[im][in][r];
            }
        }
    }
}

// ---------------- scan kernels ----------------
// y[t] = a*y[t-1] + s[t].  |a| <= 0.03125, so a 12-term window reconstructs
// any chunk's carry-in to ~1e-18 -> chunk-parallel scan is exact in fp32.
// CHUNK=32: 128 chunks x 2048 h = 1024 blocks (4/CU) and only 32 dependent
// steps -> BW-bound instead of latency-bound.

__global__ void scan_init_kernel(const float* __restrict__ S,
                                 const float* __restrict__ a_diag,
                                 float* __restrict__ yinit,
                                 int H, int chunk, int W) {
    int tid = blockIdx.x * blockDim.x + threadIdx.x;
    int h = tid % H, c = tid / H;
    float a = a_diag[h];
    float y = 0.f;
    if (c > 0) {
        int t0 = c * chunk;
        for (int t = t0 - W; t < t0; ++t)
            y = fmaf(a, y, S[(size_t)t * H + h]);
    }
    yinit[(size_t)c * H + h] = y;
}

__global__ void scan_run_kernel(const float* __restrict__ yinit,
                                const float* __restrict__ a_diag,
                                float* __restrict__ out,
                                int H, int chunk) {
    int tid = blockIdx.x * blockDim.x + threadIdx.x;
    int h = tid % H, c = tid / H;
    float a = a_diag[h];
    float y = yinit[(size_t)c * H + h];
    size_t base = (size_t)c * chunk * H + h;
    for (int t = 0; t < chunk; ++t) {
        float s = out[base + (size_t)t * H];
        y = fmaf(a, y, s);
        out[base + (size_t)t * H] = y;
    }
}

// ---------------- fallback (tiny ws): correct but slow ----------------

__global__ void gemm_fallback(const float* __restrict__ X, const float* __restrict__ B,
                              float* __restrict__ C, int M, int N, int K) {
    __shared__ float sA[16][17];
    __shared__ float sB[16][17];
    int tx = threadIdx.x, ty = threadIdx.y;
    int row = blockIdx.y * 16 + ty, col = blockIdx.x * 16 + tx;
    float acc = 0.f;
    for (int k0 = 0; k0 < K; k0 += 16) {
        sA[ty][tx] = (row < M && k0 + tx < K) ? X[(size_t)row * K + k0 + tx] : 0.f;
        sB[ty][tx] = (k0 + ty < K && col < N) ? B[(size_t)(k0 + ty) * N + col] : 0.f;
        __syncthreads();
#pragma unroll
        for (int kk = 0; kk < 16; ++kk) acc += sA[ty][kk] * sB[kk][tx];
        __syncthreads();
    }
    if (row < M && col < N) C[(size_t)row * N + col] = acc;
}

__global__ void scan_serial(float* __restrict__ out, const float* __restrict__ a_diag,
                            int T, int H) {
    int h = blockIdx.x * blockDim.x + threadIdx.x;
    if (h >= H) return;
    float a = a_diag[h], y = 0.f;
    for (int t = 0; t < T; ++t) {
        y = fmaf(a, y, out[(size_t)t * H + h]);
        out[(size_t)t * H + h] = y;
    }
}

// ---------------- launch ----------------

extern "C" void kernel_launch(void* const* d_in, const int* in_sizes, int n_in,
                              void* d_out, int out_size, void* d_ws, size_t ws_size,
                              hipStream_t stream) {
    const float* x = (const float*)d_in[0];   // (T,H)
    const float* a = (const float*)d_in[1];   // (H,)
    const float* b = (const float*)d_in[2];   // (H,H)
    float* out = (float*)d_out;               // (T,H)

    const int H = in_sizes[1];
    const int T = in_sizes[0] / H;
    const int M = T, N = H, K = H;

    const int CHUNK = 32, W = 12;

    size_t xbf_elems = (size_t)M * K;
    size_t bt_elems  = (size_t)N * K;
    int nchunks = (T % CHUNK == 0) ? T / CHUNK : 0;
    size_t need = xbf_elems * 2 + bt_elems * 2 + 256;  // yinit aliases Xbf

    bool fast = (ws_size >= need) && (M % 128 == 0) && (N % 128 == 0) &&
                (K % 64 == 0) && (H % 32 == 0) && nchunks > 0 &&
                ((xbf_elems % 4) == 0) &&
                (((size_t)nchunks * H) % 256 == 0) &&
                ((size_t)nchunks * H * 4 <= xbf_elems * 2);  // yinit fits in Xbf

    if (fast) {
        unsigned short* Xbf = (unsigned short*)d_ws;
        unsigned short* Bt  = Xbf + xbf_elems;
        float* yinit = (float*)d_ws;   // aliases Xbf: dead after gemm reads it

        int n4 = (int)(xbf_elems / 4);
        cast_x_kernel<<<(n4 + 255) / 256, 256, 0, stream>>>(x, Xbf, n4);

        dim3 tb(32, 8), tg(H / 32, H / 32);
        transpose_cast_b<<<tg, tb, 0, stream>>>(b, Bt, H);

        dim3 gg(N / 128, M / 128);
        gemm_bf16<<<gg, 256, 0, stream>>>(Xbf, Bt, out, M, N, K);

        int nth = nchunks * H;
        scan_init_kernel<<<nth / 256, 256, 0, stream>>>(out, a, yinit, H, CHUNK, W);
        scan_run_kernel<<<nth / 256, 256, 0, stream>>>(yinit, a, out, H, CHUNK);
    } else {
        dim3 tb(16, 16), tg((N + 15) / 16, (M + 15) / 16);
        gemm_fallback<<<tg, tb, 0, stream>>>(x, b, out, M, N, K);
        scan_serial<<<(H + 255) / 256, 256, 0, stream>>>(out, a, T, H);
    }
}

// Round 3
// 154.617 us; speedup vs baseline: 1.2066x; 1.0224x over previous
//
#include <hip/hip_runtime.h>
#include <cstdint>
#include <cstddef>

typedef short bf16x8 __attribute__((ext_vector_type(8)));
typedef float f32x4 __attribute__((ext_vector_type(4)));

__device__ __forceinline__ unsigned short f2bf(float f) {
    union { float f; uint32_t u; } v; v.f = f;
    uint32_t r = v.u + 0x7FFFu + ((v.u >> 16) & 1u);   // round-to-nearest-even
    return (unsigned short)(r >> 16);
}

// ---------------- prep: cast X to bf16  +  transpose-cast B ----------------
// blocks [0, castBlocks): X fp32 -> bf16 (float4/ushort4)
// blocks [castBlocks, ...): B (K,N) -> Bt (N,K) bf16 via 32x33 LDS tile

__global__ void prep_kernel(const float* __restrict__ X,
                            unsigned short* __restrict__ Xbf, int n4,
                            const float* __restrict__ B,
                            unsigned short* __restrict__ Bt, int H,
                            int castBlocks) {
    if ((int)blockIdx.x < castBlocks) {
        int i = blockIdx.x * 256 + threadIdx.x;
        if (i < n4) {
            float4 v = ((const float4*)X)[i];
            ushort4 o;
            o.x = f2bf(v.x); o.y = f2bf(v.y); o.z = f2bf(v.z); o.w = f2bf(v.w);
            ((ushort4*)Xbf)[i] = o;
        }
        return;
    }
    __shared__ float tile[32][33];
    int tb = blockIdx.x - castBlocks;
    int tilesPerRow = H / 32;
    int bx = (tb % tilesPerRow) * 32;   // n tile
    int by = (tb / tilesPerRow) * 32;   // k tile
    int tx = threadIdx.x & 31, ty = threadIdx.x >> 5;   // (32,8)
#pragma unroll
    for (int i = 0; i < 32; i += 8)
        tile[ty + i][tx] = B[(size_t)(by + ty + i) * H + bx + tx];
    __syncthreads();
#pragma unroll
    for (int i = 0; i < 32; i += 8)
        Bt[(size_t)(bx + ty + i) * H + by + tx] = f2bf(tile[tx][ty + i]);
}

// ---------------- GEMM: C = A(bf16, MxK) * Bt(bf16, NxK)^T -> fp32 MxN -------
// 128x128 tile, BK=64, double-buffered LDS (2x32KB), one barrier per K-step,
// prefetch issued right after the barrier so it overlaps the MFMA phase.
// XOR-swizzled LDS layout (0 bank conflicts, verified round 2).
// XCD swizzle: each XCD owns a 4-m-panel strip (A working set 2MB fits L2).
// Epilogue also writes rows with (row%32)>=20 into `warm` (carry-in windows
// for the chunk-parallel scan), eliminating the separate scan_init kernel.

__device__ __forceinline__ void stage_tile(
    const unsigned short* __restrict__ Ab, const unsigned short* __restrict__ Bb,
    unsigned short* sAp, unsigned short* sBp,
    int wave, int srow, int scol, int k0, int K)
{
#pragma unroll
    for (int i = 0; i < 4; ++i) {
        const int t = wave * 4 + i;
        const unsigned short* ga = Ab + (size_t)(t * 8 + srow) * K + (k0 + scol);
        __builtin_amdgcn_global_load_lds(
            (const __attribute__((address_space(1))) void*)ga,
            (__attribute__((address_space(3))) void*)(sAp + t * 512),
            16, 0, 0);
        const unsigned short* gb = Bb + (size_t)(t * 8 + srow) * K + (k0 + scol);
        __builtin_amdgcn_global_load_lds(
            (const __attribute__((address_space(1))) void*)gb,
            (__attribute__((address_space(3))) void*)(sBp + t * 512),
            16, 0, 0);
    }
}

__global__ __launch_bounds__(256, 2) void gemm_bf16(
    const unsigned short* __restrict__ A,
    const unsigned short* __restrict__ Bt,
    float* __restrict__ C, float* __restrict__ warm,
    int M, int N, int K, int gridM)
{
    __shared__ __attribute__((aligned(16))) unsigned short sA[2][128 * 64];
    __shared__ __attribute__((aligned(16))) unsigned short sB[2][128 * 64];

    const int tid  = threadIdx.x;
    const int wave = tid >> 6;
    const int lane = tid & 63;

    // XCD-aware block swizzle: XCD x gets m-panels [x*mPerX, (x+1)*mPerX)
    int b = blockIdx.x;
    int mt, nt;
    if ((gridM & 7) == 0) {
        int x = b & 7, g = b >> 3;
        int mPerX = gridM >> 3;
        mt = x * mPerX + (g % mPerX);
        nt = g / mPerX;
    } else {
        mt = b % gridM;
        nt = b / gridM;
    }
    const int m0 = mt * 128;
    const int n0 = nt * 128;

    // staging indices (swizzled: lane l -> row t*8+(l>>3), colblk (l&7)^(l>>3))
    const int srow = lane >> 3;
    const int scol = ((lane & 7) ^ srow) * 8;

    // fragment indices
    const int quad = lane >> 4;
    const int l16  = lane & 15;
    const int wm = wave >> 1;
    const int wn = wave & 1;

    const int s7 = l16 & 7;
    const int rbaseA = (wm * 8 + (l16 >> 3)) * 1024 + s7 * 128;
    const int rbaseB = (wn * 8 + (l16 >> 3)) * 1024 + s7 * 128;
    const int coff0 = (quad ^ s7) * 16;
    const int coff1 = ((quad + 4) ^ s7) * 16;

    f32x4 acc[4][4];
#pragma unroll
    for (int i = 0; i < 4; ++i)
#pragma unroll
        for (int j = 0; j < 4; ++j)
            acc[i][j] = (f32x4){0.f, 0.f, 0.f, 0.f};

    const unsigned short* Ab = A  + (size_t)m0 * K;
    const unsigned short* Bb = Bt + (size_t)n0 * K;

#define COMPUTE(P)                                                          \
    {                                                                       \
        bf16x8 af[2][4], bfr[2][4];                                         \
        _Pragma("unroll")                                                   \
        for (int t = 0; t < 4; ++t) {                                       \
            const char* pa = (const char*)sA[P] + rbaseA + t * 2048;        \
            af[0][t]  = *(const bf16x8*)(pa + coff0);                       \
            af[1][t]  = *(const bf16x8*)(pa + coff1);                       \
            const char* pb = (const char*)sB[P] + rbaseB + t * 2048;        \
            bfr[0][t] = *(const bf16x8*)(pb + coff0);                       \
            bfr[1][t] = *(const bf16x8*)(pb + coff1);                       \
        }                                                                   \
        _Pragma("unroll")                                                   \
        for (int kk = 0; kk < 2; ++kk)                                      \
            _Pragma("unroll")                                               \
            for (int im = 0; im < 4; ++im)                                  \
                _Pragma("unroll")                                           \
                for (int in = 0; in < 4; ++in)                              \
                    acc[im][in] = __builtin_amdgcn_mfma_f32_16x16x32_bf16(  \
                        af[kk][im], bfr[kk][in], acc[im][in], 0, 0, 0);     \
    }

    stage_tile(Ab, Bb, sA[0], sB[0], wave, srow, scol, 0, K);
    for (int k0 = 0; k0 < K; k0 += 128) {
        __syncthreads();                        // buf0 ready; buf1 free
        stage_tile(Ab, Bb, sA[1], sB[1], wave, srow, scol, k0 + 64, K);
        COMPUTE(0)
        __syncthreads();                        // buf1 ready; buf0 free
        if (k0 + 128 < K)
            stage_tile(Ab, Bb, sA[0], sB[0], wave, srow, scol, k0 + 128, K);
        COMPUTE(1)
    }
#undef COMPUTE

    // epilogue: D[row][col], col=l16, row=quad*4+r per 16x16 tile.
    // rows with (row%32) in [20,32) also go to warm[(row/32)*12 + row%32-20][col]
#pragma unroll
    for (int im = 0; im < 4; ++im) {
#pragma unroll
        for (int in = 0; in < 4; ++in) {
            int col = n0 + wn * 64 + in * 16 + l16;
#pragma unroll
            for (int r = 0; r < 4; ++r) {
                int row = m0 + wm * 64 + im * 16 + quad * 4 + r;
                float v = acc[im][in][r];
                C[(size_t)row * N + col] = v;
                int rm = row & 31;
                if (warm && rm >= 20)
                    warm[((size_t)(row >> 5) * 12 + (rm - 20)) * N + col] = v;
            }
        }
    }
}

// ---------------- fused scan ----------------
// y[t] = a*y[t-1] + s[t].  |a| <= 0.03125 -> 12-term warm-up reconstructs the
// carry-in to ~1e-18. Warm-up rows come from `warm` (written by the GEMM, never
// overwritten) so the in-place chunk scan has no inter-block race.

__global__ void scan_kernel(const float* __restrict__ warm,
                            const float* __restrict__ a_diag,
                            float* __restrict__ out,
                            int H, int chunk) {
    int tid = blockIdx.x * blockDim.x + threadIdx.x;
    int h = tid % H, c = tid / H;
    float a = a_diag[h];
    float y = 0.f;
    if (c > 0) {
        const float* w = warm + (size_t)(c - 1) * 12 * H + h;
#pragma unroll
        for (int i = 0; i < 12; ++i)
            y = fmaf(a, y, w[(size_t)i * H]);
    }
    size_t base = (size_t)c * chunk * H + h;
    float s = out[base];
#pragma unroll 4
    for (int t = 0; t < chunk - 1; ++t) {
        float snext = out[base + (size_t)(t + 1) * H];   // prefetch ahead of store
        y = fmaf(a, y, s);
        out[base + (size_t)t * H] = y;
        s = snext;
    }
    y = fmaf(a, y, s);
    out[base + (size_t)(chunk - 1) * H] = y;
}

// ---------------- mid-tier scan (ws too small for warm buffer) ----------------

__global__ void scan_init_kernel(const float* __restrict__ S,
                                 const float* __restrict__ a_diag,
                                 float* __restrict__ yinit,
                                 int H, int chunk, int W) {
    int tid = blockIdx.x * blockDim.x + threadIdx.x;
    int h = tid % H, c = tid / H;
    float a = a_diag[h];
    float y = 0.f;
    if (c > 0) {
        int t0 = c * chunk;
        for (int t = t0 - W; t < t0; ++t)
            y = fmaf(a, y, S[(size_t)t * H + h]);
    }
    yinit[(size_t)c * H + h] = y;
}

__global__ void scan_run_kernel(const float* __restrict__ yinit,
                                const float* __restrict__ a_diag,
                                float* __restrict__ out,
                                int H, int chunk) {
    int tid = blockIdx.x * blockDim.x + threadIdx.x;
    int h = tid % H, c = tid / H;
    float a = a_diag[h];
    float y = yinit[(size_t)c * H + h];
    size_t base = (size_t)c * chunk * H + h;
    float s = out[base];
#pragma unroll 4
    for (int t = 0; t < chunk - 1; ++t) {
        float snext = out[base + (size_t)(t + 1) * H];
        y = fmaf(a, y, s);
        out[base + (size_t)t * H] = y;
        s = snext;
    }
    y = fmaf(a, y, s);
    out[base + (size_t)(chunk - 1) * H] = y;
}

// ---------------- fallback (tiny ws): correct but slow ----------------

__global__ void gemm_fallback(const float* __restrict__ X, const float* __restrict__ B,
                              float* __restrict__ C, int M, int N, int K) {
    __shared__ float sA[16][17];
    __shared__ float sB[16][17];
    int tx = threadIdx.x, ty = threadIdx.y;
    int row = blockIdx.y * 16 + ty, col = blockIdx.x * 16 + tx;
    float acc = 0.f;
    for (int k0 = 0; k0 < K; k0 += 16) {
        sA[ty][tx] = (row < M && k0 + tx < K) ? X[(size_t)row * K + k0 + tx] : 0.f;
        sB[ty][tx] = (k0 + ty < K && col < N) ? B[(size_t)(k0 + ty) * N + col] : 0.f;
        __syncthreads();
#pragma unroll
        for (int kk = 0; kk < 16; ++kk) acc += sA[ty][kk] * sB[kk][tx];
        __syncthreads();
    }
    if (row < M && col < N) C[(size_t)row * N + col] = acc;
}

__global__ void scan_serial(float* __restrict__ out, const float* __restrict__ a_diag,
                            int T, int H) {
    int h = blockIdx.x * blockDim.x + threadIdx.x;
    if (h >= H) return;
    float a = a_diag[h], y = 0.f;
    for (int t = 0; t < T; ++t) {
        y = fmaf(a, y, out[(size_t)t * H + h]);
        out[(size_t)t * H + h] = y;
    }
}

// ---------------- launch ----------------

extern "C" void kernel_launch(void* const* d_in, const int* in_sizes, int n_in,
                              void* d_out, int out_size, void* d_ws, size_t ws_size,
                              hipStream_t stream) {
    const float* x = (const float*)d_in[0];   // (T,H)
    const float* a = (const float*)d_in[1];   // (H,)
    const float* b = (const float*)d_in[2];   // (H,H)
    float* out = (float*)d_out;               // (T,H)

    const int H = in_sizes[1];
    const int T = in_sizes[0] / H;
    const int M = T, N = H, K = H;

    const int CHUNK = 32, W = 12;

    size_t xbf_elems = (size_t)M * K;
    size_t bt_elems  = (size_t)N * K;
    int nchunks = (T % CHUNK == 0) ? T / CHUNK : 0;
    size_t warm_elems = (size_t)(M / 32) * 12 * N;

    size_t need1 = xbf_elems * 2 + bt_elems * 2 + warm_elems * 4 + 256;
    size_t need2 = xbf_elems * 2 + bt_elems * 2 + 256;   // yinit aliases Xbf

    bool shape_ok = (M % 128 == 0) && (N % 128 == 0) && (K % 128 == 0) &&
                    (H % 32 == 0) && nchunks > 0 && ((xbf_elems % 4) == 0) &&
                    (((size_t)nchunks * H) % 256 == 0) && (M % 32 == 0);
    int gridM = M / 128, gridN = N / 128;

    if (shape_ok && ws_size >= need1) {
        unsigned short* Xbf = (unsigned short*)d_ws;
        unsigned short* Bt  = Xbf + xbf_elems;
        float* warm = (float*)(Bt + bt_elems);

        int n4 = (int)(xbf_elems / 4);
        int castBlocks = (n4 + 255) / 256;
        int transBlocks = (H / 32) * (H / 32);
        prep_kernel<<<castBlocks + transBlocks, 256, 0, stream>>>(
            x, Xbf, n4, b, Bt, H, castBlocks);

        gemm_bf16<<<gridM * gridN, 256, 0, stream>>>(Xbf, Bt, out, warm,
                                                     M, N, K, gridM);

        int nth = nchunks * H;
        scan_kernel<<<nth / 256, 256, 0, stream>>>(warm, a, out, H, CHUNK);
    } else if (shape_ok && ws_size >= need2 &&
               ((size_t)nchunks * H * 4 <= xbf_elems * 2)) {
        unsigned short* Xbf = (unsigned short*)d_ws;
        unsigned short* Bt  = Xbf + xbf_elems;
        float* yinit = (float*)d_ws;   // aliases Xbf: dead after gemm reads it

        int n4 = (int)(xbf_elems / 4);
        int castBlocks = (n4 + 255) / 256;
        int transBlocks = (H / 32) * (H / 32);
        prep_kernel<<<castBlocks + transBlocks, 256, 0, stream>>>(
            x, Xbf, n4, b, Bt, H, castBlocks);

        gemm_bf16<<<gridM * gridN, 256, 0, stream>>>(Xbf, Bt, out, nullptr,
                                                     M, N, K, gridM);

        int nth = nchunks * H;
        scan_init_kernel<<<nth / 256, 256, 0, stream>>>(out, a, yinit, H, CHUNK, W);
        scan_run_kernel<<<nth / 256, 256, 0, stream>>>(yinit, a, out, H, CHUNK);
    } else {
        dim3 tb(16, 16), tg((N + 15) / 16, (M + 15) / 16);
        gemm_fallback<<<tg, tb, 0, stream>>>(x, b, out, M, N, K);
        scan_serial<<<(H + 255) / 256, 256, 0, stream>>>(out, a, T, H);
    }
}

// Round 4
// 149.847 us; speedup vs baseline: 1.2450x; 1.0318x over previous
//
#include <hip/hip_runtime.h>
#include <cstdint>
#include <cstddef>

typedef short bf16x8 __attribute__((ext_vector_type(8)));
typedef float f32x4 __attribute__((ext_vector_type(4)));

__device__ __forceinline__ unsigned short f2bf(float f) {
    union { float f; uint32_t u; } v; v.f = f;
    uint32_t r = v.u + 0x7FFFu + ((v.u >> 16) & 1u);   // round-to-nearest-even
    return (unsigned short)(r >> 16);
}

// ---------------- prep: cast X to bf16  +  transpose-cast B ----------------

__global__ void prep_kernel(const float* __restrict__ X,
                            unsigned short* __restrict__ Xbf, int n4,
                            const float* __restrict__ B,
                            unsigned short* __restrict__ Bt, int H,
                            int castBlocks) {
    if ((int)blockIdx.x < castBlocks) {
        int i = blockIdx.x * 256 + threadIdx.x;
        if (i < n4) {
            float4 v = ((const float4*)X)[i];
            ushort4 o;
            o.x = f2bf(v.x); o.y = f2bf(v.y); o.z = f2bf(v.z); o.w = f2bf(v.w);
            ((ushort4*)Xbf)[i] = o;
        }
        return;
    }
    __shared__ float tile[32][33];
    int tb = blockIdx.x - castBlocks;
    int tilesPerRow = H / 32;
    int bx = (tb % tilesPerRow) * 32;   // n tile
    int by = (tb / tilesPerRow) * 32;   // k tile
    int tx = threadIdx.x & 31, ty = threadIdx.x >> 5;   // (32,8)
#pragma unroll
    for (int i = 0; i < 32; i += 8)
        tile[ty + i][tx] = B[(size_t)(by + ty + i) * H + bx + tx];
    __syncthreads();
#pragma unroll
    for (int i = 0; i < 32; i += 8)
        Bt[(size_t)(bx + ty + i) * H + by + tx] = f2bf(tile[tx][ty + i]);
}

// ---------------- GEMM: S = A(bf16, MxK) * Bt(bf16, NxK)^T, split-K ---------
// Round-2 proven structure: 128x128 tile, BK=64, single 32KB LDS buffer,
// stage -> sync -> compute -> sync, XOR-swizzled layout (0 bank conflicts).
// Split-K (nk=2): kt=0 blocks write S0 (=d_out), kt=1 blocks write S1 (ws);
// the scan adds the two streams. 1024 blocks -> 4 blocks/CU, 16 waves/CU.
// XCD swizzle: XCD x owns m-panels [x*gridM/8, ...) for L2 A-reuse.
// kt=0 epilogue also saves rows with (row%32)>=20 into `warm` (S0-partial
// carry-in windows; S1's warm rows are read from S1 directly).

__device__ __forceinline__ void stage_tile(
    const unsigned short* __restrict__ Ab, const unsigned short* __restrict__ Bb,
    unsigned short* sAp, unsigned short* sBp,
    int wave, int srow, int scol, int k0, int K)
{
#pragma unroll
    for (int i = 0; i < 4; ++i) {
        const int t = wave * 4 + i;
        const unsigned short* ga = Ab + (size_t)(t * 8 + srow) * K + (k0 + scol);
        __builtin_amdgcn_global_load_lds(
            (const __attribute__((address_space(1))) void*)ga,
            (__attribute__((address_space(3))) void*)(sAp + t * 512),
            16, 0, 0);
        const unsigned short* gb = Bb + (size_t)(t * 8 + srow) * K + (k0 + scol);
        __builtin_amdgcn_global_load_lds(
            (const __attribute__((address_space(1))) void*)gb,
            (__attribute__((address_space(3))) void*)(sBp + t * 512),
            16, 0, 0);
    }
}

__global__ __launch_bounds__(256, 4) void gemm_bf16(
    const unsigned short* __restrict__ A,
    const unsigned short* __restrict__ Bt,
    float* __restrict__ S0, float* __restrict__ S1, float* __restrict__ warm,
    int M, int N, int K, int gridM, int gridN, int nk)
{
    __shared__ __attribute__((aligned(16))) unsigned short sA[128 * 64];
    __shared__ __attribute__((aligned(16))) unsigned short sB[128 * 64];

    const int tid  = threadIdx.x;
    const int wave = tid >> 6;
    const int lane = tid & 63;

    int b = blockIdx.x;
    int mt, nt, kt;
    if ((gridM & 7) == 0) {
        int x = b & 7, g = b >> 3;
        int mPerX = gridM >> 3;
        int ml = g % mPerX, g2 = g / mPerX;
        nt = g2 % gridN;
        kt = g2 / gridN;
        mt = x * mPerX + ml;
    } else {
        mt = b % gridM;
        nt = (b / gridM) % gridN;
        kt = b / (gridM * gridN);
    }
    const int m0 = mt * 128;
    const int n0 = nt * 128;
    const int ksize = K / nk;
    const int kbase = kt * ksize;

    // staging indices (swizzled: lane l -> row t*8+(l>>3), colblk (l&7)^(l>>3))
    const int srow = lane >> 3;
    const int scol = ((lane & 7) ^ srow) * 8;

    // fragment indices
    const int quad = lane >> 4;
    const int l16  = lane & 15;
    const int wm = wave >> 1;
    const int wn = wave & 1;

    const int s7 = l16 & 7;
    const int rbaseA = (wm * 8 + (l16 >> 3)) * 1024 + s7 * 128;
    const int rbaseB = (wn * 8 + (l16 >> 3)) * 1024 + s7 * 128;
    const int coff0 = (quad ^ s7) * 16;
    const int coff1 = ((quad + 4) ^ s7) * 16;

    f32x4 acc[4][4];
#pragma unroll
    for (int i = 0; i < 4; ++i)
#pragma unroll
        for (int j = 0; j < 4; ++j)
            acc[i][j] = (f32x4){0.f, 0.f, 0.f, 0.f};

    const unsigned short* Ab = A  + (size_t)m0 * K;
    const unsigned short* Bb = Bt + (size_t)n0 * K;

    for (int k0 = kbase; k0 < kbase + ksize; k0 += 64) {
        stage_tile(Ab, Bb, sA, sB, wave, srow, scol, k0, K);
        __syncthreads();
        bf16x8 af[2][4], bfr[2][4];
#pragma unroll
        for (int t = 0; t < 4; ++t) {
            const char* pa = (const char*)sA + rbaseA + t * 2048;
            af[0][t]  = *(const bf16x8*)(pa + coff0);
            af[1][t]  = *(const bf16x8*)(pa + coff1);
            const char* pb = (const char*)sB + rbaseB + t * 2048;
            bfr[0][t] = *(const bf16x8*)(pb + coff0);
            bfr[1][t] = *(const bf16x8*)(pb + coff1);
        }
#pragma unroll
        for (int kk = 0; kk < 2; ++kk)
#pragma unroll
            for (int im = 0; im < 4; ++im)
#pragma unroll
                for (int in = 0; in < 4; ++in)
                    acc[im][in] = __builtin_amdgcn_mfma_f32_16x16x32_bf16(
                        af[kk][im], bfr[kk][in], acc[im][in], 0, 0, 0);
        __syncthreads();
    }

    float* __restrict__ S = (kt == 0) ? S0 : S1;
    const bool do_warm = (kt == 0) && (warm != nullptr);
#pragma unroll
    for (int im = 0; im < 4; ++im) {
#pragma unroll
        for (int in = 0; in < 4; ++in) {
            int col = n0 + wn * 64 + in * 16 + l16;
#pragma unroll
            for (int r = 0; r < 4; ++r) {
                int row = m0 + wm * 64 + im * 16 + quad * 4 + r;
                float v = acc[im][in][r];
                S[(size_t)row * N + col] = v;
                int rm = row & 31;
                if (do_warm && rm >= 20)
                    warm[((size_t)(row >> 5) * 12 + (rm - 20)) * N + col] = v;
            }
        }
    }
}

// ---------------- scans ----------------
// y[t] = a*y[t-1] + s[t].  |a| <= 0.03125 -> 12-term warm-up reconstructs the
// carry-in to ~1e-18, so the chunk scan is race-free and exact in fp32.

// split-K scan: s[t] = out[t] (S0 partial, in-place) + S1[t].
// warm-up rows: warm (S0 partial, immutable) + S1 rows (immutable).
__global__ void scan_splitk(const float* __restrict__ warm,
                            const float* __restrict__ S1,
                            const float* __restrict__ a_diag,
                            float* __restrict__ out,
                            int H, int chunk) {
    int tid = blockIdx.x * blockDim.x + threadIdx.x;
    int h = tid % H, c = tid / H;
    float a = a_diag[h];
    float y = 0.f;
    if (c > 0) {
        const float* w0 = warm + ((size_t)(c - 1) * 12) * H + h;
        const float* w1 = S1 + ((size_t)c * chunk - 12) * H + h;
#pragma unroll
        for (int i = 0; i < 12; ++i)
            y = fmaf(a, y, w0[(size_t)i * H] + w1[(size_t)i * H]);
    }
    size_t base = (size_t)c * chunk * H + h;
    float s = out[base] + S1[base];
#pragma unroll 4
    for (int t = 0; t < chunk - 1; ++t) {
        size_t nx = base + (size_t)(t + 1) * H;
        float snext = out[nx] + S1[nx];
        y = fmaf(a, y, s);
        out[base + (size_t)t * H] = y;
        s = snext;
    }
    y = fmaf(a, y, s);
    out[base + (size_t)(chunk - 1) * H] = y;
}

// non-split scan (warm holds full sums)
__global__ void scan_kernel(const float* __restrict__ warm,
                            const float* __restrict__ a_diag,
                            float* __restrict__ out,
                            int H, int chunk) {
    int tid = blockIdx.x * blockDim.x + threadIdx.x;
    int h = tid % H, c = tid / H;
    float a = a_diag[h];
    float y = 0.f;
    if (c > 0) {
        const float* w = warm + (size_t)(c - 1) * 12 * H + h;
#pragma unroll
        for (int i = 0; i < 12; ++i)
            y = fmaf(a, y, w[(size_t)i * H]);
    }
    size_t base = (size_t)c * chunk * H + h;
    float s = out[base];
#pragma unroll 4
    for (int t = 0; t < chunk - 1; ++t) {
        float snext = out[base + (size_t)(t + 1) * H];
        y = fmaf(a, y, s);
        out[base + (size_t)t * H] = y;
        s = snext;
    }
    y = fmaf(a, y, s);
    out[base + (size_t)(chunk - 1) * H] = y;
}

// ---------------- mid-tier scan (ws too small for warm buffer) --------------

__global__ void scan_init_kernel(const float* __restrict__ S,
                                 const float* __restrict__ a_diag,
                                 float* __restrict__ yinit,
                                 int H, int chunk, int W) {
    int tid = blockIdx.x * blockDim.x + threadIdx.x;
    int h = tid % H, c = tid / H;
    float a = a_diag[h];
    float y = 0.f;
    if (c > 0) {
        int t0 = c * chunk;
        for (int t = t0 - W; t < t0; ++t)
            y = fmaf(a, y, S[(size_t)t * H + h]);
    }
    yinit[(size_t)c * H + h] = y;
}

__global__ void scan_run_kernel(const float* __restrict__ yinit,
                                const float* __restrict__ a_diag,
                                float* __restrict__ out,
                                int H, int chunk) {
    int tid = blockIdx.x * blockDim.x + threadIdx.x;
    int h = tid % H, c = tid / H;
    float a = a_diag[h];
    float y = yinit[(size_t)c * H + h];
    size_t base = (size_t)c * chunk * H + h;
    float s = out[base];
#pragma unroll 4
    for (int t = 0; t < chunk - 1; ++t) {
        float snext = out[base + (size_t)(t + 1) * H];
        y = fmaf(a, y, s);
        out[base + (size_t)t * H] = y;
        s = snext;
    }
    y = fmaf(a, y, s);
    out[base + (size_t)(chunk - 1) * H] = y;
}

// ---------------- fallback (tiny ws): correct but slow ----------------

__global__ void gemm_fallback(const float* __restrict__ X, const float* __restrict__ B,
                              float* __restrict__ C, int M, int N, int K) {
    __shared__ float sA[16][17];
    __shared__ float sB[16][17];
    int tx = threadIdx.x, ty = threadIdx.y;
    int row = blockIdx.y * 16 + ty, col = blockIdx.x * 16 + tx;
    float acc = 0.f;
    for (int k0 = 0; k0 < K; k0 += 16) {
        sA[ty][tx] = (row < M && k0 + tx < K) ? X[(size_t)row * K + k0 + tx] : 0.f;
        sB[ty][tx] = (k0 + ty < K && col < N) ? B[(size_t)(k0 + ty) * N + col] : 0.f;
        __syncthreads();
#pragma unroll
        for (int kk = 0; kk < 16; ++kk) acc += sA[ty][kk] * sB[kk][tx];
        __syncthreads();
    }
    if (row < M && col < N) C[(size_t)row * N + col] = acc;
}

__global__ void scan_serial(float* __restrict__ out, const float* __restrict__ a_diag,
                            int T, int H) {
    int h = blockIdx.x * blockDim.x + threadIdx.x;
    if (h >= H) return;
    float a = a_diag[h], y = 0.f;
    for (int t = 0; t < T; ++t) {
        y = fmaf(a, y, out[(size_t)t * H + h]);
        out[(size_t)t * H + h] = y;
    }
}

// ---------------- launch ----------------

extern "C" void kernel_launch(void* const* d_in, const int* in_sizes, int n_in,
                              void* d_out, int out_size, void* d_ws, size_t ws_size,
                              hipStream_t stream) {
    const float* x = (const float*)d_in[0];   // (T,H)
    const float* a = (const float*)d_in[1];   // (H,)
    const float* b = (const float*)d_in[2];   // (H,H)
    float* out = (float*)d_out;               // (T,H)

    const int H = in_sizes[1];
    const int T = in_sizes[0] / H;
    const int M = T, N = H, K = H;

    const int CHUNK = 32, W = 12;

    size_t xbf_elems = (size_t)M * K;
    size_t bt_elems  = (size_t)N * K;
    size_t MN = (size_t)M * N;
    int nchunks = (T % CHUNK == 0) ? T / CHUNK : 0;
    size_t warm_elems = (size_t)(M / 32) * 12 * N;

    size_t need_sk   = xbf_elems * 2 + bt_elems * 2 + MN * 4 + warm_elems * 4 + 256;
    size_t need_warm = xbf_elems * 2 + bt_elems * 2 + warm_elems * 4 + 256;
    size_t need_mid  = xbf_elems * 2 + bt_elems * 2 + 256;

    bool shape_ok = (M % 128 == 0) && (N % 128 == 0) && (K % 128 == 0) &&
                    (H % 32 == 0) && nchunks > 0 && ((xbf_elems % 4) == 0) &&
                    (((size_t)nchunks * H) % 256 == 0) && (M % 32 == 0);
    int gridM = M / 128, gridN = N / 128;

    int n4 = (int)(xbf_elems / 4);
    int castBlocks = (n4 + 255) / 256;
    int transBlocks = (H % 32 == 0) ? (H / 32) * (H / 32) : 0;
    int nth = nchunks * H;

    if (shape_ok && (gridM % 8 == 0) && ws_size >= need_sk) {
        // split-K=2 path: 4 blocks/CU on the GEMM
        unsigned short* Xbf = (unsigned short*)d_ws;
        unsigned short* Bt  = Xbf + xbf_elems;
        float* S1   = (float*)(Bt + bt_elems);
        float* warm = S1 + MN;

        prep_kernel<<<castBlocks + transBlocks, 256, 0, stream>>>(
            x, Xbf, n4, b, Bt, H, castBlocks);

        gemm_bf16<<<gridM * gridN * 2, 256, 0, stream>>>(
            Xbf, Bt, out, S1, warm, M, N, K, gridM, gridN, 2);

        scan_splitk<<<nth / 256, 256, 0, stream>>>(warm, S1, a, out, H, CHUNK);
    } else if (shape_ok && ws_size >= need_warm) {
        unsigned short* Xbf = (unsigned short*)d_ws;
        unsigned short* Bt  = Xbf + xbf_elems;
        float* warm = (float*)(Bt + bt_elems);

        prep_kernel<<<castBlocks + transBlocks, 256, 0, stream>>>(
            x, Xbf, n4, b, Bt, H, castBlocks);

        gemm_bf16<<<gridM * gridN, 256, 0, stream>>>(
            Xbf, Bt, out, nullptr, warm, M, N, K, gridM, gridN, 1);

        scan_kernel<<<nth / 256, 256, 0, stream>>>(warm, a, out, H, CHUNK);
    } else if (shape_ok && ws_size >= need_mid &&
               ((size_t)nchunks * H * 4 <= xbf_elems * 2)) {
        unsigned short* Xbf = (unsigned short*)d_ws;
        unsigned short* Bt  = Xbf + xbf_elems;
        float* yinit = (float*)d_ws;   // aliases Xbf: dead after gemm reads it

        prep_kernel<<<castBlocks + transBlocks, 256, 0, stream>>>(
            x, Xbf, n4, b, Bt, H, castBlocks);

        gemm_bf16<<<gridM * gridN, 256, 0, stream>>>(
            Xbf, Bt, out, nullptr, nullptr, M, N, K, gridM, gridN, 1);

        scan_init_kernel<<<nth / 256, 256, 0, stream>>>(out, a, yinit, H, CHUNK, W);
        scan_run_kernel<<<nth / 256, 256, 0, stream>>>(yinit, a, out, H, CHUNK);
    } else {
        dim3 tb(16, 16), tg((N + 15) / 16, (M + 15) / 16);
        gemm_fallback<<<tg, tb, 0, stream>>>(x, b, out, M, N, K);
        scan_serial<<<(H + 255) / 256, 256, 0, stream>>>(out, a, T, H);
    }
}

// Round 5
// 143.207 us; speedup vs baseline: 1.3028x; 1.0464x over previous
//
#include <hip/hip_runtime.h>
#include <cstdint>
#include <cstddef>

typedef short bf16x8 __attribute__((ext_vector_type(8)));
typedef float f32x4 __attribute__((ext_vector_type(4)));

__device__ __forceinline__ unsigned short f2bf(float f) {
    union { float f; uint32_t u; } v; v.f = f;
    uint32_t r = v.u + 0x7FFFu + ((v.u >> 16) & 1u);   // round-to-nearest-even
    return (unsigned short)(r >> 16);
}

__device__ __forceinline__ float bf2f(unsigned short u) {
    union { uint32_t u; float f; } v; v.u = (uint32_t)u << 16;
    return v.f;
}

// ---------------- prep: cast X to bf16  +  transpose-cast B ----------------

__global__ void prep_kernel(const float* __restrict__ X,
                            unsigned short* __restrict__ Xbf, int n4,
                            const float* __restrict__ B,
                            unsigned short* __restrict__ Bt, int H,
                            int castBlocks) {
    if ((int)blockIdx.x < castBlocks) {
        int i = blockIdx.x * 256 + threadIdx.x;
        if (i < n4) {
            float4 v = ((const float4*)X)[i];
            ushort4 o;
            o.x = f2bf(v.x); o.y = f2bf(v.y); o.z = f2bf(v.z); o.w = f2bf(v.w);
            ((ushort4*)Xbf)[i] = o;
        }
        return;
    }
    __shared__ float tile[32][33];
    int tb = blockIdx.x - castBlocks;
    int tilesPerRow = H / 32;
    int bx = (tb % tilesPerRow) * 32;   // n tile
    int by = (tb / tilesPerRow) * 32;   // k tile
    int tx = threadIdx.x & 31, ty = threadIdx.x >> 5;   // (32,8)
#pragma unroll
    for (int i = 0; i < 32; i += 8)
        tile[ty + i][tx] = B[(size_t)(by + ty + i) * H + bx + tx];
    __syncthreads();
#pragma unroll
    for (int i = 0; i < 32; i += 8)
        Bt[(size_t)(bx + ty + i) * H + by + tx] = f2bf(tile[tx][ty + i]);
}

// ---------------- GEMM core (shared staging helper) ----------------
// 128x128 tile, BK=64, single 32KB LDS buffer, XOR-swizzled layout
// (0 bank conflicts, verified round 2), global_load_lds width=16.

__device__ __forceinline__ void stage_tile(
    const unsigned short* __restrict__ Ab, const unsigned short* __restrict__ Bb,
    unsigned short* sAp, unsigned short* sBp,
    int wave, int srow, int scol, int k0, int K)
{
#pragma unroll
    for (int i = 0; i < 4; ++i) {
        const int t = wave * 4 + i;
        const unsigned short* ga = Ab + (size_t)(t * 8 + srow) * K + (k0 + scol);
        __builtin_amdgcn_global_load_lds(
            (const __attribute__((address_space(1))) void*)ga,
            (__attribute__((address_space(3))) void*)(sAp + t * 512),
            16, 0, 0);
        const unsigned short* gb = Bb + (size_t)(t * 8 + srow) * K + (k0 + scol);
        __builtin_amdgcn_global_load_lds(
            (const __attribute__((address_space(1))) void*)gb,
            (__attribute__((address_space(3))) void*)(sBp + t * 512),
            16, 0, 0);
    }
}

// Split-K=2 GEMM, bf16 outputs: kt=0 -> S0, kt=1 -> S1 (both in ws, immutable
// afterwards -> race-free scan, no warm buffer needed).
// XCD swizzle: XCD x owns m-panels [x*gridM/8, ...) for L2 A-reuse.

__global__ __launch_bounds__(256, 4) void gemm_sk_bf16out(
    const unsigned short* __restrict__ A,
    const unsigned short* __restrict__ Bt,
    unsigned short* __restrict__ S0, unsigned short* __restrict__ S1,
    int M, int N, int K, int gridM, int gridN)
{
    __shared__ __attribute__((aligned(16))) unsigned short sA[128 * 64];
    __shared__ __attribute__((aligned(16))) unsigned short sB[128 * 64];

    const int tid  = threadIdx.x;
    const int wave = tid >> 6;
    const int lane = tid & 63;

    int b = blockIdx.x;
    int mt, nt, kt;
    if ((gridM & 7) == 0) {
        int x = b & 7, g = b >> 3;
        int mPerX = gridM >> 3;
        int ml = g % mPerX, g2 = g / mPerX;
        nt = g2 % gridN;
        kt = g2 / gridN;
        mt = x * mPerX + ml;
    } else {
        mt = b % gridM;
        nt = (b / gridM) % gridN;
        kt = b / (gridM * gridN);
    }
    const int m0 = mt * 128;
    const int n0 = nt * 128;
    const int ksize = K / 2;
    const int kbase = kt * ksize;

    const int srow = lane >> 3;
    const int scol = ((lane & 7) ^ srow) * 8;

    const int quad = lane >> 4;
    const int l16  = lane & 15;
    const int wm = wave >> 1;
    const int wn = wave & 1;

    const int s7 = l16 & 7;
    const int rbaseA = (wm * 8 + (l16 >> 3)) * 1024 + s7 * 128;
    const int rbaseB = (wn * 8 + (l16 >> 3)) * 1024 + s7 * 128;
    const int coff0 = (quad ^ s7) * 16;
    const int coff1 = ((quad + 4) ^ s7) * 16;

    f32x4 acc[4][4];
#pragma unroll
    for (int i = 0; i < 4; ++i)
#pragma unroll
        for (int j = 0; j < 4; ++j)
            acc[i][j] = (f32x4){0.f, 0.f, 0.f, 0.f};

    const unsigned short* Ab = A  + (size_t)m0 * K;
    const unsigned short* Bb = Bt + (size_t)n0 * K;

    for (int k0 = kbase; k0 < kbase + ksize; k0 += 64) {
        stage_tile(Ab, Bb, sA, sB, wave, srow, scol, k0, K);
        __syncthreads();
        bf16x8 af[2][4], bfr[2][4];
#pragma unroll
        for (int t = 0; t < 4; ++t) {
            const char* pa = (const char*)sA + rbaseA + t * 2048;
            af[0][t]  = *(const bf16x8*)(pa + coff0);
            af[1][t]  = *(const bf16x8*)(pa + coff1);
            const char* pb = (const char*)sB + rbaseB + t * 2048;
            bfr[0][t] = *(const bf16x8*)(pb + coff0);
            bfr[1][t] = *(const bf16x8*)(pb + coff1);
        }
#pragma unroll
        for (int kk = 0; kk < 2; ++kk)
#pragma unroll
            for (int im = 0; im < 4; ++im)
#pragma unroll
                for (int in = 0; in < 4; ++in)
                    acc[im][in] = __builtin_amdgcn_mfma_f32_16x16x32_bf16(
                        af[kk][im], bfr[kk][in], acc[im][in], 0, 0, 0);
        __syncthreads();
    }

    unsigned short* __restrict__ S = (kt == 0) ? S0 : S1;
#pragma unroll
    for (int im = 0; im < 4; ++im) {
#pragma unroll
        for (int in = 0; in < 4; ++in) {
            int col = n0 + wn * 64 + in * 16 + l16;
#pragma unroll
            for (int r = 0; r < 4; ++r) {
                int row = m0 + wm * 64 + im * 16 + quad * 4 + r;
                S[(size_t)row * N + col] = f2bf(acc[im][in][r]);
            }
        }
    }
}

// Non-split fp32-out GEMM (mid-tier fallback; round-3 proven path).
__global__ __launch_bounds__(256, 4) void gemm_f32out(
    const unsigned short* __restrict__ A,
    const unsigned short* __restrict__ Bt,
    float* __restrict__ C, int M, int N, int K, int gridM)
{
    __shared__ __attribute__((aligned(16))) unsigned short sA[128 * 64];
    __shared__ __attribute__((aligned(16))) unsigned short sB[128 * 64];

    const int tid  = threadIdx.x;
    const int wave = tid >> 6;
    const int lane = tid & 63;

    int b = blockIdx.x;
    int mt, nt;
    if ((gridM & 7) == 0) {
        int x = b & 7, g = b >> 3;
        int mPerX = gridM >> 3;
        mt = x * mPerX + (g % mPerX);
        nt = g / mPerX;
    } else {
        mt = b % gridM;
        nt = b / gridM;
    }
    const int m0 = mt * 128;
    const int n0 = nt * 128;

    const int srow = lane >> 3;
    const int scol = ((lane & 7) ^ srow) * 8;
    const int quad = lane >> 4;
    const int l16  = lane & 15;
    const int wm = wave >> 1;
    const int wn = wave & 1;
    const int s7 = l16 & 7;
    const int rbaseA = (wm * 8 + (l16 >> 3)) * 1024 + s7 * 128;
    const int rbaseB = (wn * 8 + (l16 >> 3)) * 1024 + s7 * 128;
    const int coff0 = (quad ^ s7) * 16;
    const int coff1 = ((quad + 4) ^ s7) * 16;

    f32x4 acc[4][4];
#pragma unroll
    for (int i = 0; i < 4; ++i)
#pragma unroll
        for (int j = 0; j < 4; ++j)
            acc[i][j] = (f32x4){0.f, 0.f, 0.f, 0.f};

    const unsigned short* Ab = A  + (size_t)m0 * K;
    const unsigned short* Bb = Bt + (size_t)n0 * K;

    for (int k0 = 0; k0 < K; k0 += 64) {
        stage_tile(Ab, Bb, sA, sB, wave, srow, scol, k0, K);
        __syncthreads();
        bf16x8 af[2][4], bfr[2][4];
#pragma unroll
        for (int t = 0; t < 4; ++t) {
            const char* pa = (const char*)sA + rbaseA + t * 2048;
            af[0][t]  = *(const bf16x8*)(pa + coff0);
            af[1][t]  = *(const bf16x8*)(pa + coff1);
            const char* pb = (const char*)sB + rbaseB + t * 2048;
            bfr[0][t] = *(const bf16x8*)(pb + coff0);
            bfr[1][t] = *(const bf16x8*)(pb + coff1);
        }
#pragma unroll
        for (int kk = 0; kk < 2; ++kk)
#pragma unroll
            for (int im = 0; im < 4; ++im)
#pragma unroll
                for (int in = 0; in < 4; ++in)
                    acc[im][in] = __builtin_amdgcn_mfma_f32_16x16x32_bf16(
                        af[kk][im], bfr[kk][in], acc[im][in], 0, 0, 0);
        __syncthreads();
    }

#pragma unroll
    for (int im = 0; im < 4; ++im)
#pragma unroll
        for (int in = 0; in < 4; ++in) {
            int col = n0 + wn * 64 + in * 16 + l16;
#pragma unroll
            for (int r = 0; r < 4; ++r) {
                int row = m0 + wm * 64 + im * 16 + quad * 4 + r;
                C[(size_t)row * N + col] = acc[im][in][r];
            }
        }
}

// ---------------- scan (fast path) ----------------
// y[t] = a*y[t-1] + (S0[t]+S1[t]).  |a| <= 2^-5 -> 8-term warm-up
// reconstructs the carry-in to ~1e-12. S0/S1 are immutable (out is a separate
// buffer) -> race-free. 2 channels per thread (ushort2 loads, float2 stores,
// two independent FMA chains for ILP).

__global__ void scan_splitk_bf16(const unsigned short* __restrict__ S0,
                                 const unsigned short* __restrict__ S1,
                                 const float* __restrict__ a_diag,
                                 float* __restrict__ out,
                                 int H2, int chunk) {
    int tid = blockIdx.x * blockDim.x + threadIdx.x;
    int hp = tid % H2, c = tid / H2;
    float2 av = ((const float2*)a_diag)[hp];
    const ushort2* S0v = (const ushort2*)S0;
    const ushort2* S1v = (const ushort2*)S1;
    float2* outv = (float2*)out;

    float y0 = 0.f, y1 = 0.f;
    if (c > 0) {
        size_t r0 = (size_t)c * chunk - 8;
#pragma unroll
        for (int i = 0; i < 8; ++i) {
            size_t idx = (r0 + i) * H2 + hp;
            ushort2 u = S0v[idx], w = S1v[idx];
            y0 = fmaf(av.x, y0, bf2f(u.x) + bf2f(w.x));
            y1 = fmaf(av.y, y1, bf2f(u.y) + bf2f(w.y));
        }
    }
    size_t idx = (size_t)c * chunk * H2 + hp;
    ushort2 u = S0v[idx], w = S1v[idx];
    for (int t = 0; t < chunk - 1; ++t) {
        size_t idx2 = idx + H2;
        ushort2 un = S0v[idx2], wn = S1v[idx2];   // prefetch next row
        y0 = fmaf(av.x, y0, bf2f(u.x) + bf2f(w.x));
        y1 = fmaf(av.y, y1, bf2f(u.y) + bf2f(w.y));
        outv[idx] = make_float2(y0, y1);
        u = un; w = wn; idx = idx2;
    }
    y0 = fmaf(av.x, y0, bf2f(u.x) + bf2f(w.x));
    y1 = fmaf(av.y, y1, bf2f(u.y) + bf2f(w.y));
    outv[idx] = make_float2(y0, y1);
}

// ---------------- mid-tier scan (fp32 S in out, in-place) --------------

__global__ void scan_init_kernel(const float* __restrict__ S,
                                 const float* __restrict__ a_diag,
                                 float* __restrict__ yinit,
                                 int H, int chunk, int W) {
    int tid = blockIdx.x * blockDim.x + threadIdx.x;
    int h = tid % H, c = tid / H;
    float a = a_diag[h];
    float y = 0.f;
    if (c > 0) {
        int t0 = c * chunk;
        for (int t = t0 - W; t < t0; ++t)
            y = fmaf(a, y, S[(size_t)t * H + h]);
    }
    yinit[(size_t)c * H + h] = y;
}

__global__ void scan_run_kernel(const float* __restrict__ yinit,
                                const float* __restrict__ a_diag,
                                float* __restrict__ out,
                                int H, int chunk) {
    int tid = blockIdx.x * blockDim.x + threadIdx.x;
    int h = tid % H, c = tid / H;
    float a = a_diag[h];
    float y = yinit[(size_t)c * H + h];
    size_t base = (size_t)c * chunk * H + h;
    float s = out[base];
#pragma unroll 4
    for (int t = 0; t < chunk - 1; ++t) {
        float snext = out[base + (size_t)(t + 1) * H];
        y = fmaf(a, y, s);
        out[base + (size_t)t * H] = y;
        s = snext;
    }
    y = fmaf(a, y, s);
    out[base + (size_t)(chunk - 1) * H] = y;
}

// ---------------- fallback (tiny ws): correct but slow ----------------

__global__ void gemm_fallback(const float* __restrict__ X, const float* __restrict__ B,
                              float* __restrict__ C, int M, int N, int K) {
    __shared__ float sA[16][17];
    __shared__ float sB[16][17];
    int tx = threadIdx.x, ty = threadIdx.y;
    int row = blockIdx.y * 16 + ty, col = blockIdx.x * 16 + tx;
    float acc = 0.f;
    for (int k0 = 0; k0 < K; k0 += 16) {
        sA[ty][tx] = (row < M && k0 + tx < K) ? X[(size_t)row * K + k0 + tx] : 0.f;
        sB[ty][tx] = (k0 + ty < K && col < N) ? B[(size_t)(k0 + ty) * N + col] : 0.f;
        __syncthreads();
#pragma unroll
        for (int kk = 0; kk < 16; ++kk) acc += sA[ty][kk] * sB[kk][tx];
        __syncthreads();
    }
    if (row < M && col < N) C[(size_t)row * N + col] = acc;
}

__global__ void scan_serial(float* __restrict__ out, const float* __restrict__ a_diag,
                            int T, int H) {
    int h = blockIdx.x * blockDim.x + threadIdx.x;
    if (h >= H) return;
    float a = a_diag[h], y = 0.f;
    for (int t = 0; t < T; ++t) {
        y = fmaf(a, y, out[(size_t)t * H + h]);
        out[(size_t)t * H + h] = y;
    }
}

// ---------------- launch ----------------

extern "C" void kernel_launch(void* const* d_in, const int* in_sizes, int n_in,
                              void* d_out, int out_size, void* d_ws, size_t ws_size,
                              hipStream_t stream) {
    const float* x = (const float*)d_in[0];   // (T,H)
    const float* a = (const float*)d_in[1];   // (H,)
    const float* b = (const float*)d_in[2];   // (H,H)
    float* out = (float*)d_out;               // (T,H)

    const int H = in_sizes[1];
    const int T = in_sizes[0] / H;
    const int M = T, N = H, K = H;

    const int CHUNK = 32, W = 12;

    size_t xbf_elems = (size_t)M * K;
    size_t bt_elems  = (size_t)N * K;
    size_t MN = (size_t)M * N;
    int nchunks = (T % CHUNK == 0) ? T / CHUNK : 0;

    size_t need_sk  = (xbf_elems + bt_elems + 2 * MN) * 2 + 256;
    size_t need_mid = xbf_elems * 2 + bt_elems * 2 + 256;

    bool shape_ok = (M % 128 == 0) && (N % 128 == 0) && (K % 128 == 0) &&
                    (H % 32 == 0) && nchunks > 0 && ((xbf_elems % 4) == 0) &&
                    (((size_t)nchunks * H) % 256 == 0);
    int gridM = M / 128, gridN = N / 128;

    int n4 = (int)(xbf_elems / 4);
    int castBlocks = (n4 + 255) / 256;
    int transBlocks = (H % 32 == 0) ? (H / 32) * (H / 32) : 0;

    int H2 = H / 2;
    size_t nth2 = (size_t)nchunks * H2;

    if (shape_ok && (gridM % 8 == 0) && (H % 4 == 0) &&
        (nth2 % 256 == 0) && ws_size >= need_sk) {
        // fast path: split-K=2, bf16 partials in ws, race-free bf16 scan
        unsigned short* Xbf = (unsigned short*)d_ws;
        unsigned short* Bt  = Xbf + xbf_elems;
        unsigned short* S0  = Bt + bt_elems;
        unsigned short* S1  = S0 + MN;

        prep_kernel<<<castBlocks + transBlocks, 256, 0, stream>>>(
            x, Xbf, n4, b, Bt, H, castBlocks);

        gemm_sk_bf16out<<<gridM * gridN * 2, 256, 0, stream>>>(
            Xbf, Bt, S0, S1, M, N, K, gridM, gridN);

        scan_splitk_bf16<<<(int)(nth2 / 256), 256, 0, stream>>>(
            S0, S1, a, out, H2, CHUNK);
    } else if (shape_ok && ws_size >= need_mid &&
               ((size_t)nchunks * H * 4 <= xbf_elems * 2)) {
        unsigned short* Xbf = (unsigned short*)d_ws;
        unsigned short* Bt  = Xbf + xbf_elems;
        float* yinit = (float*)d_ws;   // aliases Xbf: dead after gemm reads it

        prep_kernel<<<castBlocks + transBlocks, 256, 0, stream>>>(
            x, Xbf, n4, b, Bt, H, castBlocks);

        gemm_f32out<<<gridM * gridN, 256, 0, stream>>>(
            Xbf, Bt, out, M, N, K, gridM);

        int nth = nchunks * H;
        scan_init_kernel<<<nth / 256, 256, 0, stream>>>(out, a, yinit, H, CHUNK, W);
        scan_run_kernel<<<nth / 256, 256, 0, stream>>>(yinit, a, out, H, CHUNK);
    } else {
        dim3 tb(16, 16), tg((N + 15) / 16, (M + 15) / 16);
        gemm_fallback<<<tg, tb, 0, stream>>>(x, b, out, M, N, K);
        scan_serial<<<(H + 255) / 256, 256, 0, stream>>>(out, a, T, H);
    }
}

// Round 6
// 140.417 us; speedup vs baseline: 1.3287x; 1.0199x over previous
//
#include <hip/hip_runtime.h>
#include <cstdint>
#include <cstddef>

typedef short bf16x8 __attribute__((ext_vector_type(8)));
typedef float f32x4 __attribute__((ext_vector_type(4)));

__device__ __forceinline__ unsigned short f2bf(float f) {
    union { float f; uint32_t u; } v; v.f = f;
    uint32_t r = v.u + 0x7FFFu + ((v.u >> 16) & 1u);   // round-to-nearest-even
    return (unsigned short)(r >> 16);
}

__device__ __forceinline__ float bf2f(unsigned short u) {
    union { uint32_t u; float f; } v; v.u = (uint32_t)u << 16;
    return v.f;
}

// ---------------- prep: cast X to bf16  +  transpose-cast B ----------------

__global__ void prep_kernel(const float* __restrict__ X,
                            unsigned short* __restrict__ Xbf, int n4,
                            const float* __restrict__ B,
                            unsigned short* __restrict__ Bt, int H,
                            int castBlocks) {
    if ((int)blockIdx.x < castBlocks) {
        int i = blockIdx.x * 256 + threadIdx.x;
        if (i < n4) {
            float4 v = ((const float4*)X)[i];
            ushort4 o;
            o.x = f2bf(v.x); o.y = f2bf(v.y); o.z = f2bf(v.z); o.w = f2bf(v.w);
            ((ushort4*)Xbf)[i] = o;
        }
        return;
    }
    __shared__ float tile[32][33];
    int tb = blockIdx.x - castBlocks;
    int tilesPerRow = H / 32;
    int bx = (tb % tilesPerRow) * 32;   // n tile
    int by = (tb / tilesPerRow) * 32;   // k tile
    int tx = threadIdx.x & 31, ty = threadIdx.x >> 5;   // (32,8)
#pragma unroll
    for (int i = 0; i < 32; i += 8)
        tile[ty + i][tx] = B[(size_t)(by + ty + i) * H + bx + tx];
    __syncthreads();
#pragma unroll
    for (int i = 0; i < 32; i += 8)
        Bt[(size_t)(bx + ty + i) * H + by + tx] = f2bf(tile[tx][ty + i]);
}

// ---------------- fast GEMM: S = A * Bt^T, split-K=2, bf16 out --------------
// Block tile 256x128, BK=64, 4 waves, wave tile 128x64 (8x4 grid of 16x16x32
// MFMA) -> FLOP per LDS-byte 42.7 vs 32 for the old 64x64 wave tile (the
// measured binding pipe). Single 48KB LDS buffer, XOR-swizzled layout
// (verified 0 conflicts), global_load_lds width=16 staging (A: 8 instr/wave,
// B: 4). kt=0 -> S0, kt=1 -> S1 (immutable afterwards -> race-free scan).
// XCD swizzle: XCD x owns m-panels [x*gridM/8, ...) for L2 A-reuse.

__global__ __launch_bounds__(256, 2) void gemm_sk_bf16out(
    const unsigned short* __restrict__ A,
    const unsigned short* __restrict__ Bt,
    unsigned short* __restrict__ S0, unsigned short* __restrict__ S1,
    int M, int N, int K, int gridM, int gridN)
{
    __shared__ __attribute__((aligned(16))) unsigned short sA[256 * 64]; // 32KB
    __shared__ __attribute__((aligned(16))) unsigned short sB[128 * 64]; // 16KB

    const int tid  = threadIdx.x;
    const int wave = tid >> 6;
    const int lane = tid & 63;

    int b = blockIdx.x;
    int mt, nt, kt;
    if ((gridM & 7) == 0) {
        int x = b & 7, g = b >> 3;
        int mPerX = gridM >> 3;
        int ml = g % mPerX, g2 = g / mPerX;
        nt = g2 % gridN;
        kt = g2 / gridN;
        mt = x * mPerX + ml;
    } else {
        mt = b % gridM;
        nt = (b / gridM) % gridN;
        kt = b / (gridM * gridN);
    }
    const int m0 = mt * 256;
    const int n0 = nt * 128;
    const int ksize = K / 2;
    const int kbase = kt * ksize;

    // staging indices (proven swizzle): lane l of block-instr t loads
    // row t*8+(l>>3), global colblk (l&7)^(l>>3) -> LDS slot l*16B.
    const int srow = lane >> 3;
    const int scol = ((lane & 7) ^ srow) * 8;

    // fragment indices (16x16x32, HW-verified layout)
    const int quad = lane >> 4;
    const int l16  = lane & 15;
    const int wm = wave >> 1;       // m half (128 rows)
    const int wn = wave & 1;        // n half (64 cols)
    const int s7 = l16 & 7;
    const int c0 = (quad ^ s7) * 16;        // kk=0 colblk byte offset
    const int c1 = ((quad + 4) ^ s7) * 16;  // kk=1

    f32x4 acc[8][4];
#pragma unroll
    for (int i = 0; i < 8; ++i)
#pragma unroll
        for (int j = 0; j < 4; ++j)
            acc[i][j] = (f32x4){0.f, 0.f, 0.f, 0.f};

    const unsigned short* Ab = A  + (size_t)m0 * K;
    const unsigned short* Bb = Bt + (size_t)n0 * K;

    const int rA = (wm * 16 + (l16 >> 3)) * 1024 + s7 * 128;  // + im*2048
    const int rB = (wn * 8  + (l16 >> 3)) * 1024 + s7 * 128;  // + in*2048

    for (int k0 = kbase; k0 < kbase + ksize; k0 += 64) {
#pragma unroll
        for (int i = 0; i < 8; ++i) {
            const int t = wave * 8 + i;
            const unsigned short* ga = Ab + (size_t)(t * 8 + srow) * K + (k0 + scol);
            __builtin_amdgcn_global_load_lds(
                (const __attribute__((address_space(1))) void*)ga,
                (__attribute__((address_space(3))) void*)(sA + t * 512),
                16, 0, 0);
        }
#pragma unroll
        for (int i = 0; i < 4; ++i) {
            const int t = wave * 4 + i;
            const unsigned short* gb = Bb + (size_t)(t * 8 + srow) * K + (k0 + scol);
            __builtin_amdgcn_global_load_lds(
                (const __attribute__((address_space(1))) void*)gb,
                (__attribute__((address_space(3))) void*)(sB + t * 512),
                16, 0, 0);
        }
        __syncthreads();

#pragma unroll
        for (int kk = 0; kk < 2; ++kk) {
            const int co = kk ? c1 : c0;
            bf16x8 af[8], bfr[4];
#pragma unroll
            for (int im = 0; im < 8; ++im)
                af[im] = *(const bf16x8*)((const char*)sA + rA + im * 2048 + co);
#pragma unroll
            for (int in = 0; in < 4; ++in)
                bfr[in] = *(const bf16x8*)((const char*)sB + rB + in * 2048 + co);
#pragma unroll
            for (int im = 0; im < 8; ++im)
#pragma unroll
                for (int in = 0; in < 4; ++in)
                    acc[im][in] = __builtin_amdgcn_mfma_f32_16x16x32_bf16(
                        af[im], bfr[in], acc[im][in], 0, 0, 0);
        }
        __syncthreads();
    }

    unsigned short* __restrict__ S = (kt == 0) ? S0 : S1;
#pragma unroll
    for (int im = 0; im < 8; ++im) {
#pragma unroll
        for (int in = 0; in < 4; ++in) {
            int col = n0 + wn * 64 + in * 16 + l16;
#pragma unroll
            for (int r = 0; r < 4; ++r) {
                int row = m0 + wm * 128 + im * 16 + quad * 4 + r;
                S[(size_t)row * N + col] = f2bf(acc[im][in][r]);
            }
        }
    }
}

// ---------------- mid-tier GEMM (fp32 out, non-split; round-3 proven) -------

__device__ __forceinline__ void stage_tile128(
    const unsigned short* __restrict__ Ab, const unsigned short* __restrict__ Bb,
    unsigned short* sAp, unsigned short* sBp,
    int wave, int srow, int scol, int k0, int K)
{
#pragma unroll
    for (int i = 0; i < 4; ++i) {
        const int t = wave * 4 + i;
        const unsigned short* ga = Ab + (size_t)(t * 8 + srow) * K + (k0 + scol);
        __builtin_amdgcn_global_load_lds(
            (const __attribute__((address_space(1))) void*)ga,
            (__attribute__((address_space(3))) void*)(sAp + t * 512),
            16, 0, 0);
        const unsigned short* gb = Bb + (size_t)(t * 8 + srow) * K + (k0 + scol);
        __builtin_amdgcn_global_load_lds(
            (const __attribute__((address_space(1))) void*)gb,
            (__attribute__((address_space(3))) void*)(sBp + t * 512),
            16, 0, 0);
    }
}

__global__ __launch_bounds__(256, 4) void gemm_f32out(
    const unsigned short* __restrict__ A,
    const unsigned short* __restrict__ Bt,
    float* __restrict__ C, int M, int N, int K, int gridM)
{
    __shared__ __attribute__((aligned(16))) unsigned short sA[128 * 64];
    __shared__ __attribute__((aligned(16))) unsigned short sB[128 * 64];

    const int tid  = threadIdx.x;
    const int wave = tid >> 6;
    const int lane = tid & 63;

    int b = blockIdx.x;
    int mt, nt;
    if ((gridM & 7) == 0) {
        int x = b & 7, g = b >> 3;
        int mPerX = gridM >> 3;
        mt = x * mPerX + (g % mPerX);
        nt = g / mPerX;
    } else {
        mt = b % gridM;
        nt = b / gridM;
    }
    const int m0 = mt * 128;
    const int n0 = nt * 128;

    const int srow = lane >> 3;
    const int scol = ((lane & 7) ^ srow) * 8;
    const int quad = lane >> 4;
    const int l16  = lane & 15;
    const int wm = wave >> 1;
    const int wn = wave & 1;
    const int s7 = l16 & 7;
    const int rbaseA = (wm * 8 + (l16 >> 3)) * 1024 + s7 * 128;
    const int rbaseB = (wn * 8 + (l16 >> 3)) * 1024 + s7 * 128;
    const int coff0 = (quad ^ s7) * 16;
    const int coff1 = ((quad + 4) ^ s7) * 16;

    f32x4 acc[4][4];
#pragma unroll
    for (int i = 0; i < 4; ++i)
#pragma unroll
        for (int j = 0; j < 4; ++j)
            acc[i][j] = (f32x4){0.f, 0.f, 0.f, 0.f};

    const unsigned short* Ab = A  + (size_t)m0 * K;
    const unsigned short* Bb = Bt + (size_t)n0 * K;

    for (int k0 = 0; k0 < K; k0 += 64) {
        stage_tile128(Ab, Bb, sA, sB, wave, srow, scol, k0, K);
        __syncthreads();
        bf16x8 af[2][4], bfr[2][4];
#pragma unroll
        for (int t = 0; t < 4; ++t) {
            const char* pa = (const char*)sA + rbaseA + t * 2048;
            af[0][t]  = *(const bf16x8*)(pa + coff0);
            af[1][t]  = *(const bf16x8*)(pa + coff1);
            const char* pb = (const char*)sB + rbaseB + t * 2048;
            bfr[0][t] = *(const bf16x8*)(pb + coff0);
            bfr[1][t] = *(const bf16x8*)(pb + coff1);
        }
#pragma unroll
        for (int kk = 0; kk < 2; ++kk)
#pragma unroll
            for (int im = 0; im < 4; ++im)
#pragma unroll
                for (int in = 0; in < 4; ++in)
                    acc[im][in] = __builtin_amdgcn_mfma_f32_16x16x32_bf16(
                        af[kk][im], bfr[kk][in], acc[im][in], 0, 0, 0);
        __syncthreads();
    }

#pragma unroll
    for (int im = 0; im < 4; ++im)
#pragma unroll
        for (int in = 0; in < 4; ++in) {
            int col = n0 + wn * 64 + in * 16 + l16;
#pragma unroll
            for (int r = 0; r < 4; ++r) {
                int row = m0 + wm * 64 + im * 16 + quad * 4 + r;
                C[(size_t)row * N + col] = acc[im][in][r];
            }
        }
}

// ---------------- scan (fast path) ----------------
// y[t] = a*y[t-1] + (S0[t]+S1[t]).  |a| <= 2^-5 -> 8-term warm-up
// reconstructs the carry-in to ~1e-12. S0/S1 immutable -> race-free.
// CHUNK=16: 256 chunks x 1024 hp = 1024 blocks (4/CU), 24-deep dep chain.

__global__ void scan_splitk_bf16(const unsigned short* __restrict__ S0,
                                 const unsigned short* __restrict__ S1,
                                 const float* __restrict__ a_diag,
                                 float* __restrict__ out,
                                 int H2, int chunk) {
    int tid = blockIdx.x * blockDim.x + threadIdx.x;
    int hp = tid % H2, c = tid / H2;
    float2 av = ((const float2*)a_diag)[hp];
    const ushort2* S0v = (const ushort2*)S0;
    const ushort2* S1v = (const ushort2*)S1;
    float2* outv = (float2*)out;

    float y0 = 0.f, y1 = 0.f;
    if (c > 0) {
        size_t r0 = (size_t)c * chunk - 8;
#pragma unroll
        for (int i = 0; i < 8; ++i) {
            size_t idx = (r0 + i) * H2 + hp;
            ushort2 u = S0v[idx], w = S1v[idx];
            y0 = fmaf(av.x, y0, bf2f(u.x) + bf2f(w.x));
            y1 = fmaf(av.y, y1, bf2f(u.y) + bf2f(w.y));
        }
    }
    size_t idx = (size_t)c * chunk * H2 + hp;
    ushort2 u = S0v[idx], w = S1v[idx];
    for (int t = 0; t < chunk - 1; ++t) {
        size_t idx2 = idx + H2;
        ushort2 un = S0v[idx2], wn = S1v[idx2];   // prefetch next row
        y0 = fmaf(av.x, y0, bf2f(u.x) + bf2f(w.x));
        y1 = fmaf(av.y, y1, bf2f(u.y) + bf2f(w.y));
        outv[idx] = make_float2(y0, y1);
        u = un; w = wn; idx = idx2;
    }
    y0 = fmaf(av.x, y0, bf2f(u.x) + bf2f(w.x));
    y1 = fmaf(av.y, y1, bf2f(u.y) + bf2f(w.y));
    outv[idx] = make_float2(y0, y1);
}

// ---------------- mid-tier scan (fp32 S in out, in-place) --------------

__global__ void scan_init_kernel(const float* __restrict__ S,
                                 const float* __restrict__ a_diag,
                                 float* __restrict__ yinit,
                                 int H, int chunk, int W) {
    int tid = blockIdx.x * blockDim.x + threadIdx.x;
    int h = tid % H, c = tid / H;
    float a = a_diag[h];
    float y = 0.f;
    if (c > 0) {
        int t0 = c * chunk;
        for (int t = t0 - W; t < t0; ++t)
            y = fmaf(a, y, S[(size_t)t * H + h]);
    }
    yinit[(size_t)c * H + h] = y;
}

__global__ void scan_run_kernel(const float* __restrict__ yinit,
                                const float* __restrict__ a_diag,
                                float* __restrict__ out,
                                int H, int chunk) {
    int tid = blockIdx.x * blockDim.x + threadIdx.x;
    int h = tid % H, c = tid / H;
    float a = a_diag[h];
    float y = yinit[(size_t)c * H + h];
    size_t base = (size_t)c * chunk * H + h;
    float s = out[base];
#pragma unroll 4
    for (int t = 0; t < chunk - 1; ++t) {
        float snext = out[base + (size_t)(t + 1) * H];
        y = fmaf(a, y, s);
        out[base + (size_t)t * H] = y;
        s = snext;
    }
    y = fmaf(a, y, s);
    out[base + (size_t)(chunk - 1) * H] = y;
}

// ---------------- fallback (tiny ws): correct but slow ----------------

__global__ void gemm_fallback(const float* __restrict__ X, const float* __restrict__ B,
                              float* __restrict__ C, int M, int N, int K) {
    __shared__ float sA[16][17];
    __shared__ float sB[16][17];
    int tx = threadIdx.x, ty = threadIdx.y;
    int row = blockIdx.y * 16 + ty, col = blockIdx.x * 16 + tx;
    float acc = 0.f;
    for (int k0 = 0; k0 < K; k0 += 16) {
        sA[ty][tx] = (row < M && k0 + tx < K) ? X[(size_t)row * K + k0 + tx] : 0.f;
        sB[ty][tx] = (k0 + ty < K && col < N) ? B[(size_t)(k0 + ty) * N + col] : 0.f;
        __syncthreads();
#pragma unroll
        for (int kk = 0; kk < 16; ++kk) acc += sA[ty][kk] * sB[kk][tx];
        __syncthreads();
    }
    if (row < M && col < N) C[(size_t)row * N + col] = acc;
}

__global__ void scan_serial(float* __restrict__ out, const float* __restrict__ a_diag,
                            int T, int H) {
    int h = blockIdx.x * blockDim.x + threadIdx.x;
    if (h >= H) return;
    float a = a_diag[h], y = 0.f;
    for (int t = 0; t < T; ++t) {
        y = fmaf(a, y, out[(size_t)t * H + h]);
        out[(size_t)t * H + h] = y;
    }
}

// ---------------- launch ----------------

extern "C" void kernel_launch(void* const* d_in, const int* in_sizes, int n_in,
                              void* d_out, int out_size, void* d_ws, size_t ws_size,
                              hipStream_t stream) {
    const float* x = (const float*)d_in[0];   // (T,H)
    const float* a = (const float*)d_in[1];   // (H,)
    const float* b = (const float*)d_in[2];   // (H,H)
    float* out = (float*)d_out;               // (T,H)

    const int H = in_sizes[1];
    const int T = in_sizes[0] / H;
    const int M = T, N = H, K = H;

    const int CHUNK = 16, W = 12;

    size_t xbf_elems = (size_t)M * K;
    size_t bt_elems  = (size_t)N * K;
    size_t MN = (size_t)M * N;
    int nchunks = (T % CHUNK == 0) ? T / CHUNK : 0;

    size_t need_sk  = (xbf_elems + bt_elems + 2 * MN) * 2 + 256;
    size_t need_mid = xbf_elems * 2 + bt_elems * 2 + 256;

    bool shape_ok = (M % 128 == 0) && (N % 128 == 0) && (K % 128 == 0) &&
                    (H % 32 == 0) && nchunks > 0 && ((xbf_elems % 4) == 0) &&
                    (((size_t)nchunks * H) % 256 == 0);
    int gridMf = M / 128;                 // mid-tier (128-tile)
    int gridM  = (M % 256 == 0) ? M / 256 : 0;  // fast path (256-tile)
    int gridN  = N / 128;

    int n4 = (int)(xbf_elems / 4);
    int castBlocks = (n4 + 255) / 256;
    int transBlocks = (H % 32 == 0) ? (H / 32) * (H / 32) : 0;

    int H2 = H / 2;
    size_t nth2 = (size_t)nchunks * H2;

    if (shape_ok && gridM > 0 && (gridM % 8 == 0) && (H % 4 == 0) &&
        (nth2 % 256 == 0) && ws_size >= need_sk) {
        // fast path: 256x128 tiles, split-K=2, bf16 partials, race-free scan
        unsigned short* Xbf = (unsigned short*)d_ws;
        unsigned short* Bt  = Xbf + xbf_elems;
        unsigned short* S0  = Bt + bt_elems;
        unsigned short* S1  = S0 + MN;

        prep_kernel<<<castBlocks + transBlocks, 256, 0, stream>>>(
            x, Xbf, n4, b, Bt, H, castBlocks);

        gemm_sk_bf16out<<<gridM * gridN * 2, 256, 0, stream>>>(
            Xbf, Bt, S0, S1, M, N, K, gridM, gridN);

        scan_splitk_bf16<<<(int)(nth2 / 256), 256, 0, stream>>>(
            S0, S1, a, out, H2, CHUNK);
    } else if (shape_ok && ws_size >= need_mid &&
               ((size_t)nchunks * H * 4 <= xbf_elems * 2)) {
        unsigned short* Xbf = (unsigned short*)d_ws;
        unsigned short* Bt  = Xbf + xbf_elems;
        float* yinit = (float*)d_ws;   // aliases Xbf: dead after gemm reads it

        prep_kernel<<<castBlocks + transBlocks, 256, 0, stream>>>(
            x, Xbf, n4, b, Bt, H, castBlocks);

        gemm_f32out<<<gridMf * gridN, 256, 0, stream>>>(
            Xbf, Bt, out, M, N, K, gridMf);

        int nth = nchunks * H;
        scan_init_kernel<<<nth / 256, 256, 0, stream>>>(out, a, yinit, H, CHUNK, W);
        scan_run_kernel<<<nth / 256, 256, 0, stream>>>(yinit, a, out, H, CHUNK);
    } else {
        dim3 tb(16, 16), tg((N + 15) / 16, (M + 15) / 16);
        gemm_fallback<<<tg, tb, 0, stream>>>(x, b, out, M, N, K);
        scan_serial<<<(H + 255) / 256, 256, 0, stream>>>(out, a, T, H);
    }
}